// Round 8
// baseline (379.441 us; speedup 1.0000x reference)
//
#include <hip/hip_runtime.h>
#include <hip/hip_bf16.h>

#define NN 1024
#define HID 128
#define NHEADS 4
#define HDD 32
#define NL 3

// ---- ws layout (float-word units) ----
constexpr int OFF_CONV = 16;
constexpr int OFF_NF   = OFF_CONV;            // 3072
constexpr int OFF_WP   = OFF_NF  + 3072;      // 384
constexpr int OFF_BP   = OFF_WP  + 384;       // 128
constexpr int OFF_WL   = OFF_BP  + 128;       // 49152
constexpr int OFF_WR   = OFF_WL  + 49152;     // 49152
constexpr int OFF_WVW  = OFF_WR  + 49152;     // 49152
constexpr int OFF_ATT  = OFF_WVW + 49152;     // 96
constexpr int OFF_GAM  = OFF_ATT + 96;        // 384
constexpr int OFF_BET  = OFF_GAM + 384;       // 384
constexpr int OFF_WN1  = OFF_BET + 384;       // 8192
constexpr int OFF_BN1  = OFF_WN1 + 8192;      // 64
constexpr int OFF_WN2  = OFF_BN1 + 64;        // 64
constexpr int OFF_BN2  = OFF_WN2 + 64;        // 1
constexpr int OFF_WD1  = OFF_BN2 + 1;         // 8192
constexpr int OFF_BD1  = OFF_WD1 + 8192;      // 64
constexpr int OFF_WD2  = OFF_BD1 + 64;        // 128
constexpr int OFF_BD2  = OFF_WD2 + 128;       // 2
constexpr int OFF_WV1  = OFF_BD2 + 2;         // 8192
constexpr int OFF_BV1  = OFF_WV1 + 8192;      // 64
constexpr int OFF_WV2  = OFF_BV1 + 64;        // 64
constexpr int OFF_BV2  = OFF_WV2 + 64;        // 1
constexpr int OFF_CONV_END = OFF_BV2 + 1;
constexpr int CONV_TOTAL = OFF_CONV_END - OFF_CONV;
constexpr int CB = (CONV_TOTAL + 255) / 256;  // convert blocks in k_pre
constexpr int OFF_MASK = 176960;              // 1024*32 uint32 words
constexpr int OFF_H    = OFF_MASK + NN*32;
constexpr int OFF_WLH  = OFF_H   + NN*HID;    // normal [i][128]
constexpr int OFF_WRH  = OFF_WLH + NN*HID;    // TRANSPOSED [dq=32][j=1024][4]
constexpr int OFF_WVH  = OFF_WRH + NN*HID;    // TRANSPOSED [dq=32][j=1024][4]
constexpr int OFF_CL   = OFF_WVH + NN*HID;    // [h][i]  0.6*att.wl
constexpr int OFF_CR   = OFF_CL  + NHEADS*NN; // [h][j]  0.6*att.wr

__device__ __forceinline__ float bf2f(unsigned short u) {
    return __uint_as_float(((unsigned)u) << 16);
}
__device__ __forceinline__ void store_out(void* out, int idx, float v, bool bf) {
    if (bf) {
        unsigned u = __float_as_uint(v);
        unsigned r = (u + 0x7FFFu + ((u >> 16) & 1u)) >> 16;
        ((unsigned short*)out)[idx] = (unsigned short)r;
    } else {
        ((float*)out)[idx] = v;
    }
}
__device__ __forceinline__ float ldraw(const void* p, int idx, bool bf) {
    return bf ? bf2f(((const unsigned short*)p)[idx]) : ((const float*)p)[idx];
}
// per-wave dtype sniff: fp32 normals have exponent field in [110,140];
// packed bf16 pairs viewed as fp32 essentially never do. Call from ALL lanes.
__device__ __forceinline__ bool detect_bf(const unsigned* nf) {
    unsigned w = nf[threadIdx.x & 63];
    int e = (int)((w >> 23) & 0xFFu);
    unsigned long long b = __ballot(e >= 110 && e <= 140);
    return __popcll(b) < 32;
}

struct P21 { const void* p[21]; };
__device__ const int g_sizes[21] = {3072,384,128,49152,49152,49152,96,384,384,
                                    8192,64,64,1,8192,64,128,2,8192,64,64,1};
__device__ const int g_dsts[21] = {OFF_NF,OFF_WP,OFF_BP,OFF_WL,OFF_WR,OFF_WVW,OFF_ATT,
                                   OFF_GAM,OFF_BET,OFF_WN1,OFF_BN1,OFF_WN2,OFF_BN2,
                                   OFF_WD1,OFF_BD1,OFF_WD2,OFF_BD2,OFF_WV1,OFF_BV1,
                                   OFF_WV2,OFF_BV2};

// ---- fused prologue: param convert | adj->bitmask | h0  (all independent:
// h0 reads RAW nf/Wp/bp with its own bf16 handling, so no ordering needed) ----
__global__ __launch_bounds__(256) void k_pre(P21 in, const void* adj, const unsigned* nf, float* ws) {
    bool bf = detect_bf(nf);
    int b = blockIdx.x, t = threadIdx.x;
    if (b < CB) {
        // convert all non-adj params to fp32 in ws
        int g = b * 256 + t;
        if (g >= CONV_TOTAL) return;
        int rem = g, s = 0;
        while (s < 21 && rem >= g_sizes[s]) { rem -= g_sizes[s]; s++; }
        if (s >= 21) return;
        ws[g_dsts[s] + rem] = ldraw(in.p[s], rem, bf);
    } else if (b < CB + NN) {
        // adj row -> packed bitmask
        int i = b - CB;
        unsigned* mask = (unsigned*)(ws + OFF_MASK);
        int lane = t & 63, wv = t >> 6;
        #pragma unroll
        for (int q = 0; q < 4; q++) {
            int seg = wv * 4 + q;
            int j = seg * 64 + lane;
            float v = ldraw(adj, i * NN + j, bf);
            unsigned long long bl = __ballot(v > 0.5f);
            if (lane == 0) {
                mask[i * 32 + seg * 2]     = (unsigned)bl;
                mask[i * 32 + seg * 2 + 1] = (unsigned)(bl >> 32);
            }
        }
    } else {
        // h0 = relu(nf @ Wp + bp), raw reads: 2 nodes per block
        int bb = b - CB - NN;
        int i = bb * 2 + (t >> 7), c = t & 127;
        float a = ldraw(in.p[2], c, bf);                     // bp
        #pragma unroll
        for (int k = 0; k < 3; k++)
            a += ldraw(in.p[0], i * 3 + k, bf) * ldraw(in.p[1], k * HID + c, bf);
        ws[OFF_H + i * HID + c] = fmaxf(a, 0.0f);
    }
}

// ---- per layer: wlh = h@Wl (normal + cl), wrh/wvh = h@{Wr,Wv} (transposed + cr) ----
__global__ __launch_bounds__(128) void k_mm3(float* ws, int l) {
    __shared__ float hs[4][HID];
    int c = threadIdx.x, i0 = blockIdx.x * 4, which = blockIdx.y;
    const float* h = ws + OFF_H;
    #pragma unroll
    for (int r = 0; r < 4; r++) hs[r][c] = h[(i0 + r) * HID + c];
    __syncthreads();
    int woff = (which == 0) ? OFF_WL : (which == 1) ? OFF_WR : OFF_WVW;
    const float* W = ws + woff + l * HID * HID;
    float a[4] = {0,0,0,0};
    #pragma unroll 4
    for (int k = 0; k < HID; k++) {
        float w = W[k * HID + c];
        #pragma unroll
        for (int r = 0; r < 4; r++) a[r] += hs[r][k] * w;
    }
    if (which == 0) {
        #pragma unroll
        for (int r = 0; r < 4; r++) ws[OFF_WLH + (i0 + r) * HID + c] = a[r];
        float att = ws[OFF_ATT + l * HDD + (c & 31)];
        #pragma unroll
        for (int r = 0; r < 4; r++) {
            float t = att * a[r];
            #pragma unroll
            for (int off = 1; off < 32; off <<= 1) t += __shfl_xor(t, off, 64);
            if ((c & 31) == 0) ws[OFF_CL + (c >> 5) * NN + (i0 + r)] = 0.6f * t;
        }
    } else {
        int doff = (which == 1) ? OFF_WRH : OFF_WVH;
        // transposed-tiled: element (j, c) -> [c>>2][j][c&3]
        #pragma unroll
        for (int r = 0; r < 4; r++)
            ws[doff + (c >> 2) * (NN * 4) + (i0 + r) * 4 + (c & 3)] = a[r];
        if (which == 1) {
            float att = ws[OFF_ATT + l * HDD + (c & 31)];
            #pragma unroll
            for (int r = 0; r < 4; r++) {
                float t = att * a[r];
                #pragma unroll
                for (int off = 1; off < 32; off <<= 1) t += __shfl_xor(t, off, 64);
                if ((c & 31) == 0) ws[OFF_CR + (c >> 5) * NN + (i0 + r)] = 0.6f * t;
            }
        }
    }
}

// ---- per layer: fused attention, 4-node-tiled, two-pass (r5-verified) ----
// Block = 512 threads = 8 waves, 4 NODES per block (grid 256 = 1 block/CU).
// Wave w: head h = w&3, node-pair p = w>>2 -> nodes iA=i0+2p, iB=iA+1.
// e_ij = 0.6*att.(wl_i+wr_j) + sum_d 0.4*att_d*|wl_id + wr_jd|  (exact leaky split)
// r7 lesson: single-pass online softmax (>=160 live floats/lane) forces the
// compiler into AGPR-shuttling (VGPR=92 reported, v_accvgpr moves per fma) and
// LOSES ~7 us vs this two-pass form. Keep live state < ~130 floats.
// This round: jc loops unroll 2 (16 float4 in flight, was 8) — the kernel is
// latency-bound at 1 block/CU (2 waves/SIMD, VALUBusy ~24%), so double the
// per-wave MLP instead of occupancy (grid is pinned at 256 by the tiling).
__global__ __launch_bounds__(512) void k_attn(float* ws, int l) {
    int t = threadIdx.x;
    int i0 = blockIdx.x * 4;
    int lane = t & 63;
    int w = t >> 6;
    int h = __builtin_amdgcn_readfirstlane(w & 3);
    int p = __builtin_amdgcn_readfirstlane(w >> 2);
    int iA = i0 + 2 * p, iB = iA + 1;

    __shared__ unsigned mrow[4][32];
    __shared__ float ebuf[8][64][33];   // 67.6 KB: e-store, then acc-reduce scratch
    __shared__ float invs[4][4];        // [node][head]
    __shared__ float agg_s[4][HID];
    __shared__ float red2[4][2][2];

    if (t < 128) mrow[t >> 5][t & 31] = ((const unsigned*)(ws + OFF_MASK))[i0 * 32 + t];
    __syncthreads();

    // per-lane 16-bit adjacency masks for both nodes: bit jc = adj of j=jc*64+lane
    unsigned mbA = 0, mbB = 0;
    #pragma unroll
    for (int jc = 0; jc < 16; jc++) {
        int wi = jc * 2 + (lane >> 5);
        mbA |= ((mrow[2 * p][wi] >> (lane & 31)) & 1u) << jc;
        mbB |= ((mrow[2 * p + 1][wi] >> (lane & 31)) & 1u) << jc;
    }

    // wave-uniform vectors -> registers (0.4 folded into att)
    float att_r[32], wlA[32], wlB[32];
    const float* attp = ws + OFF_ATT + l * HDD;
    const float* wlpA = ws + OFF_WLH + iA * HID + h * HDD;
    const float* wlpB = ws + OFF_WLH + iB * HID + h * HDD;
    #pragma unroll
    for (int d = 0; d < 32; d++) {
        att_r[d] = 0.4f * attp[d];
        wlA[d] = wlpA[d];
        wlB[d] = wlpB[d];
    }
    float clA = ws[OFF_CL + h * NN + iA];
    float clB = ws[OFF_CL + h * NN + iB];

    const float* wrT = ws + OFF_WRH + h * 8 * (NN * 4) + lane * 4;
    const float* wvT = ws + OFF_WVH + h * 8 * (NN * 4) + lane * 4;
    const float* crp = ws + OFF_CR + h * NN;

    // pass 1: e for both nodes -> LDS, track lane maxes
    float mA = -1e30f, mB = -1e30f;
    #pragma unroll 2
    for (int jc = 0; jc < 16; jc++) {
        float cr6 = crp[jc * 64 + lane];
        float dA = 0.0f, dB = 0.0f;
        #pragma unroll
        for (int dq = 0; dq < 8; dq++) {
            float4 wv4 = *(const float4*)(wrT + dq * (NN * 4) + jc * 256);
            dA = fmaf(att_r[dq*4+0], fabsf(wlA[dq*4+0] + wv4.x), dA);
            dB = fmaf(att_r[dq*4+0], fabsf(wlB[dq*4+0] + wv4.x), dB);
            dA = fmaf(att_r[dq*4+1], fabsf(wlA[dq*4+1] + wv4.y), dA);
            dB = fmaf(att_r[dq*4+1], fabsf(wlB[dq*4+1] + wv4.y), dB);
            dA = fmaf(att_r[dq*4+2], fabsf(wlA[dq*4+2] + wv4.z), dA);
            dB = fmaf(att_r[dq*4+2], fabsf(wlB[dq*4+2] + wv4.z), dB);
            dA = fmaf(att_r[dq*4+3], fabsf(wlA[dq*4+3] + wv4.w), dA);
            dB = fmaf(att_r[dq*4+3], fabsf(wlB[dq*4+3] + wv4.w), dB);
        }
        float eA = (clA + cr6) + dA; eA = ((mbA >> jc) & 1u) ? eA : -1e9f;
        float eB = (clB + cr6) + dB; eB = ((mbB >> jc) & 1u) ? eB : -1e9f;
        ebuf[w][lane][jc]      = eA;
        ebuf[w][lane][16 + jc] = eB;
        mA = fmaxf(mA, eA);
        mB = fmaxf(mB, eB);
    }
    #pragma unroll
    for (int off = 32; off > 0; off >>= 1) {
        mA = fmaxf(mA, __shfl_xor(mA, off, 64));
        mB = fmaxf(mB, __shfl_xor(mB, off, 64));
    }

    // pass 2: pe = exp(e - m) (masked -> exact 0), accumulate pe * v for both nodes
    float accA[32], accB[32];
    #pragma unroll
    for (int d = 0; d < 32; d++) { accA[d] = 0.0f; accB[d] = 0.0f; }
    float lsA = 0.0f, lsB = 0.0f;
    #pragma unroll 2
    for (int jc = 0; jc < 16; jc++) {
        float peA = __expf(ebuf[w][lane][jc]      - mA);
        float peB = __expf(ebuf[w][lane][16 + jc] - mB);
        lsA += peA; lsB += peB;
        #pragma unroll
        for (int dq = 0; dq < 8; dq++) {
            float4 v4 = *(const float4*)(wvT + dq * (NN * 4) + jc * 256);
            accA[dq*4+0] = fmaf(peA, v4.x, accA[dq*4+0]);
            accB[dq*4+0] = fmaf(peB, v4.x, accB[dq*4+0]);
            accA[dq*4+1] = fmaf(peA, v4.y, accA[dq*4+1]);
            accB[dq*4+1] = fmaf(peB, v4.y, accB[dq*4+1]);
            accA[dq*4+2] = fmaf(peA, v4.z, accA[dq*4+2]);
            accB[dq*4+2] = fmaf(peB, v4.z, accB[dq*4+2]);
            accA[dq*4+3] = fmaf(peA, v4.w, accA[dq*4+3]);
            accB[dq*4+3] = fmaf(peB, v4.w, accB[dq*4+3]);
        }
    }
    #pragma unroll
    for (int off = 32; off > 0; off >>= 1) {
        lsA += __shfl_xor(lsA, off, 64);
        lsB += __shfl_xor(lsB, off, 64);
    }
    if (lane == 0) {
        invs[2 * p][h]     = 1.0f / lsA;
        invs[2 * p + 1][h] = 1.0f / lsB;
    }
    __syncthreads();   // all e-reads done; ebuf reusable; invs visible

    // acc cross-lane reduce via LDS, 2 rounds (node = 2p + r); region = p*4+h
    float* rbuf = &ebuf[0][0][0];
    {   // round r=0: node iA
        int reg = p * 4 + h;
        #pragma unroll
        for (int d = 0; d < 32; d++) rbuf[(reg * 64 + lane) * 33 + d] = accA[d];
        __syncthreads();
        int g = t >> 6, d = lane & 31, half = lane >> 5;
        float s = 0.0f;
        #pragma unroll
        for (int lq = 0; lq < 32; lq++) s += rbuf[(g * 64 + half * 32 + lq) * 33 + d];
        s += __shfl_xor(s, 32, 64);
        int node = 2 * (g >> 2), hh = g & 3;
        if (half == 0) agg_s[node][hh * 32 + d] = s * invs[node][hh];
        __syncthreads();
    }
    {   // round r=1: node iB
        int reg = p * 4 + h;
        #pragma unroll
        for (int d = 0; d < 32; d++) rbuf[(reg * 64 + lane) * 33 + d] = accB[d];
        __syncthreads();
        int g = t >> 6, d = lane & 31, half = lane >> 5;
        float s = 0.0f;
        #pragma unroll
        for (int lq = 0; lq < 32; lq++) s += rbuf[(g * 64 + half * 32 + lq) * 33 + d];
        s += __shfl_xor(s, 32, 64);
        int node = 2 * (g >> 2) + 1, hh = g & 3;
        if (half == 0) agg_s[node][hh * 32 + d] = s * invs[node][hh];
        __syncthreads();
    }

    // layernorm + residual for the 4 nodes: t -> node n=t>>7, feature f=t&127
    {
        int n = t >> 7, f = t & 127;
        float agg = agg_s[n][f];
        float s = agg, s2 = agg * agg;
        #pragma unroll
        for (int off = 32; off > 0; off >>= 1) {
            s  += __shfl_xor(s,  off, 64);
            s2 += __shfl_xor(s2, off, 64);
        }
        int half = (t >> 6) & 1;
        if (lane == 0) { red2[n][half][0] = s; red2[n][half][1] = s2; }
        __syncthreads();
        float ts  = red2[n][0][0] + red2[n][1][0];
        float ts2 = red2[n][0][1] + red2[n][1][1];
        float mu  = ts  * (1.0f / HID);
        float var = ts2 * (1.0f / HID) - mu * mu;
        float gm = ws[OFF_GAM + l * HID + f];
        float be = ws[OFF_BET + l * HID + f];
        float o = (agg - mu) * rsqrtf(var + 1e-5f) * gm + be;
        ws[OFF_H + (i0 + n) * HID + f] += fmaxf(o, 0.0f);
    }
}

// ---- fused epilogue, 1024 threads/block ----
// blocks 0..63: node_logits + delta_mu heads, 16 nodes/block (wave = node).
// block 64: pooled mean (8 row-groups x 128 rows, unroll-16 ILP) + value head.
__global__ __launch_bounds__(1024) void k_post(float* ws, const unsigned* nf, void* out) {
    bool bf = detect_bf(nf);
    int b = blockIdx.x, t = threadIdx.x;
    if (b < 64) {
        __shared__ float hrow[16][HID];
        int n = t >> 6, tt = t & 63;
        int i = b * 16 + n;
        hrow[n][tt]      = ws[OFF_H + i * HID + tt];
        hrow[n][tt + 64] = ws[OFF_H + i * HID + tt + 64];
        __syncthreads();
        const float* Wn1 = ws + OFF_WN1;
        const float* Wd1 = ws + OFF_WD1;
        float z1 = ws[OFF_BN1 + tt], zd = ws[OFF_BD1 + tt];
        #pragma unroll 4
        for (int k = 0; k < HID; k++) {
            float hk = hrow[n][k];
            z1 += hk * Wn1[k * 64 + tt];
            zd += hk * Wd1[k * 64 + tt];
        }
        z1 = fmaxf(z1, 0.0f); zd = fmaxf(zd, 0.0f);
        float lg = z1 * ws[OFF_WN2 + tt];
        float d0 = zd * ws[OFF_WD2 + tt * 2 + 0];
        float d1 = zd * ws[OFF_WD2 + tt * 2 + 1];
        #pragma unroll
        for (int off = 32; off > 0; off >>= 1) {
            lg += __shfl_xor(lg, off, 64);
            d0 += __shfl_xor(d0, off, 64);
            d1 += __shfl_xor(d1, off, 64);
        }
        if (tt == 0) {
            store_out(out, i,              lg + ws[OFF_BN2],     bf);
            store_out(out, NN + i * 2 + 0, d0 + ws[OFF_BD2 + 0], bf);
            store_out(out, NN + i * 2 + 1, d1 + ws[OFF_BD2 + 1], bf);
        }
    } else {
        __shared__ float part[8][HID];
        __shared__ float pooled[HID];
        int g = t >> 7, c = t & 127;
        float s = 0.0f;
        #pragma unroll 16
        for (int r = 0; r < 128; r++) s += ws[OFF_H + (g * 128 + r) * HID + c];
        part[g][c] = s;
        __syncthreads();
        if (t < HID) {
            float p = 0.0f;
            #pragma unroll
            for (int gg = 0; gg < 8; gg++) p += part[gg][t];
            pooled[t] = p * (1.0f / NN);
        }
        __syncthreads();
        if (t < 64) {
            float z = ws[OFF_BV1 + t];
            float z1 = 0.0f;
            #pragma unroll 8
            for (int k = 0; k < HID; k += 2) {
                z  += pooled[k]     * ws[OFF_WV1 + k * 64 + t];
                z1 += pooled[k + 1] * ws[OFF_WV1 + (k + 1) * 64 + t];
            }
            z = fmaxf(z + z1, 0.0f);
            float pv = z * ws[OFF_WV2 + t];
            #pragma unroll
            for (int off = 32; off > 0; off >>= 1) pv += __shfl_xor(pv, off, 64);
            if (t == 0) store_out(out, 3072, pv + ws[OFF_BV2], bf);
        }
    }
}

extern "C" void kernel_launch(void* const* d_in, const int* in_sizes, int n_in,
                              void* d_out, int out_size, void* d_ws, size_t ws_size,
                              hipStream_t stream) {
    float* ws = (float*)d_ws;
    const unsigned* nf = (const unsigned*)d_in[0];

    P21 ptrs;
    const int map[21] = {0,2,3,4,5,6,7,8,9,10,11,12,13,14,15,16,17,18,19,20,21};
    for (int s = 0; s < 21; s++) ptrs.p[s] = d_in[map[s]];

    // prologue: convert (CB blocks) | mask (NN blocks) | h0 (NN/2 blocks)
    k_pre<<<CB + NN + NN / 2, 256, 0, stream>>>(ptrs, d_in[1], nf, ws);

    for (int l = 0; l < NL; l++) {
        k_mm3<<<dim3(NN / 4, 3), 128, 0, stream>>>(ws, l);
        k_attn<<<NN / 4, 512, 0, stream>>>(ws, l);
    }

    k_post<<<65, 1024, 0, stream>>>(ws, nf, d_out);
}

// Round 9
// 248.755 us; speedup vs baseline: 1.5254x; 1.5254x over previous
//
#include <hip/hip_runtime.h>
#include <hip/hip_bf16.h>

#define NN 1024
#define HID 128
#define NHEADS 4
#define HDD 32
#define NL 3

// ---- ws layout (float-word units) ----
constexpr int OFF_CONV = 16;
constexpr int OFF_NF   = OFF_CONV;            // 3072
constexpr int OFF_WP   = OFF_NF  + 3072;      // 384
constexpr int OFF_BP   = OFF_WP  + 384;       // 128
constexpr int OFF_WL   = OFF_BP  + 128;       // 49152
constexpr int OFF_WR   = OFF_WL  + 49152;     // 49152
constexpr int OFF_WVW  = OFF_WR  + 49152;     // 49152
constexpr int OFF_ATT  = OFF_WVW + 49152;     // 96
constexpr int OFF_GAM  = OFF_ATT + 96;        // 384
constexpr int OFF_BET  = OFF_GAM + 384;       // 384
constexpr int OFF_WN1  = OFF_BET + 384;       // 8192
constexpr int OFF_BN1  = OFF_WN1 + 8192;      // 64
constexpr int OFF_WN2  = OFF_BN1 + 64;        // 64
constexpr int OFF_BN2  = OFF_WN2 + 64;        // 1
constexpr int OFF_WD1  = OFF_BN2 + 1;         // 8192
constexpr int OFF_BD1  = OFF_WD1 + 8192;      // 64
constexpr int OFF_WD2  = OFF_BD1 + 64;        // 128
constexpr int OFF_BD2  = OFF_WD2 + 128;       // 2
constexpr int OFF_WV1  = OFF_BD2 + 2;         // 8192
constexpr int OFF_BV1  = OFF_WV1 + 8192;      // 64
constexpr int OFF_WV2  = OFF_BV1 + 64;        // 64
constexpr int OFF_BV2  = OFF_WV2 + 64;        // 1
constexpr int OFF_CONV_END = OFF_BV2 + 1;
constexpr int CONV_TOTAL = OFF_CONV_END - OFF_CONV;
constexpr int CB = (CONV_TOTAL + 255) / 256;  // convert blocks in k_pre
constexpr int OFF_MASK = 176960;              // 1024*32 uint32 words
constexpr int OFF_H    = OFF_MASK + NN*32;
constexpr int OFF_WLH  = OFF_H   + NN*HID;    // normal [i][128]
constexpr int OFF_WRH  = OFF_WLH + NN*HID;    // TRANSPOSED [dq=32][j=1024][4]
constexpr int OFF_WVH  = OFF_WRH + NN*HID;    // TRANSPOSED [dq=32][j=1024][4]
constexpr int OFF_CL   = OFF_WVH + NN*HID;    // [h][i]  0.6*att.wl
constexpr int OFF_CR   = OFF_CL  + NHEADS*NN; // [h][j]  0.6*att.wr

__device__ __forceinline__ float bf2f(unsigned short u) {
    return __uint_as_float(((unsigned)u) << 16);
}
__device__ __forceinline__ void store_out(void* out, int idx, float v, bool bf) {
    if (bf) {
        unsigned u = __float_as_uint(v);
        unsigned r = (u + 0x7FFFu + ((u >> 16) & 1u)) >> 16;
        ((unsigned short*)out)[idx] = (unsigned short)r;
    } else {
        ((float*)out)[idx] = v;
    }
}
__device__ __forceinline__ float ldraw(const void* p, int idx, bool bf) {
    return bf ? bf2f(((const unsigned short*)p)[idx]) : ((const float*)p)[idx];
}
// per-wave dtype sniff: fp32 normals have exponent field in [110,140];
// packed bf16 pairs viewed as fp32 essentially never do. Call from ALL lanes.
__device__ __forceinline__ bool detect_bf(const unsigned* nf) {
    unsigned w = nf[threadIdx.x & 63];
    int e = (int)((w >> 23) & 0xFFu);
    unsigned long long b = __ballot(e >= 110 && e <= 140);
    return __popcll(b) < 32;
}
// async global->LDS copy, 16B per lane. LDS dest must be WAVE-UNIFORM base;
// HW writes lane i at base + i*16. Global src is per-lane. (m03/m97/m104)
__device__ __forceinline__ void gld_lds16(const float* g, float* l) {
    __builtin_amdgcn_global_load_lds(
        (const __attribute__((address_space(1))) void*)g,
        (__attribute__((address_space(3))) void*)l, 16, 0, 0);
}

struct P21 { const void* p[21]; };
__device__ const int g_sizes[21] = {3072,384,128,49152,49152,49152,96,384,384,
                                    8192,64,64,1,8192,64,128,2,8192,64,64,1};
__device__ const int g_dsts[21] = {OFF_NF,OFF_WP,OFF_BP,OFF_WL,OFF_WR,OFF_WVW,OFF_ATT,
                                   OFF_GAM,OFF_BET,OFF_WN1,OFF_BN1,OFF_WN2,OFF_BN2,
                                   OFF_WD1,OFF_BD1,OFF_WD2,OFF_BD2,OFF_WV1,OFF_BV1,
                                   OFF_WV2,OFF_BV2};

// ---- fused prologue: param convert | adj->bitmask | h0  (all independent:
// h0 reads RAW nf/Wp/bp with its own bf16 handling, so no ordering needed) ----
__global__ __launch_bounds__(256) void k_pre(P21 in, const void* adj, const unsigned* nf, float* ws) {
    bool bf = detect_bf(nf);
    int b = blockIdx.x, t = threadIdx.x;
    if (b < CB) {
        // convert all non-adj params to fp32 in ws
        int g = b * 256 + t;
        if (g >= CONV_TOTAL) return;
        int rem = g, s = 0;
        while (s < 21 && rem >= g_sizes[s]) { rem -= g_sizes[s]; s++; }
        if (s >= 21) return;
        ws[g_dsts[s] + rem] = ldraw(in.p[s], rem, bf);
    } else if (b < CB + NN) {
        // adj row -> packed bitmask
        int i = b - CB;
        unsigned* mask = (unsigned*)(ws + OFF_MASK);
        int lane = t & 63, wv = t >> 6;
        #pragma unroll
        for (int q = 0; q < 4; q++) {
            int seg = wv * 4 + q;
            int j = seg * 64 + lane;
            float v = ldraw(adj, i * NN + j, bf);
            unsigned long long bl = __ballot(v > 0.5f);
            if (lane == 0) {
                mask[i * 32 + seg * 2]     = (unsigned)bl;
                mask[i * 32 + seg * 2 + 1] = (unsigned)(bl >> 32);
            }
        }
    } else {
        // h0 = relu(nf @ Wp + bp), raw reads: 2 nodes per block
        int bb = b - CB - NN;
        int i = bb * 2 + (t >> 7), c = t & 127;
        float a = ldraw(in.p[2], c, bf);                     // bp
        #pragma unroll
        for (int k = 0; k < 3; k++)
            a += ldraw(in.p[0], i * 3 + k, bf) * ldraw(in.p[1], k * HID + c, bf);
        ws[OFF_H + i * HID + c] = fmaxf(a, 0.0f);
    }
}

// ---- per layer: wlh = h@Wl (normal + cl), wrh/wvh = h@{Wr,Wv} (transposed + cr) ----
__global__ __launch_bounds__(128) void k_mm3(float* ws, int l) {
    __shared__ float hs[4][HID];
    int c = threadIdx.x, i0 = blockIdx.x * 4, which = blockIdx.y;
    const float* h = ws + OFF_H;
    #pragma unroll
    for (int r = 0; r < 4; r++) hs[r][c] = h[(i0 + r) * HID + c];
    __syncthreads();
    int woff = (which == 0) ? OFF_WL : (which == 1) ? OFF_WR : OFF_WVW;
    const float* W = ws + woff + l * HID * HID;
    float a[4] = {0,0,0,0};
    #pragma unroll 4
    for (int k = 0; k < HID; k++) {
        float w = W[k * HID + c];
        #pragma unroll
        for (int r = 0; r < 4; r++) a[r] += hs[r][k] * w;
    }
    if (which == 0) {
        #pragma unroll
        for (int r = 0; r < 4; r++) ws[OFF_WLH + (i0 + r) * HID + c] = a[r];
        float att = ws[OFF_ATT + l * HDD + (c & 31)];
        #pragma unroll
        for (int r = 0; r < 4; r++) {
            float t = att * a[r];
            #pragma unroll
            for (int off = 1; off < 32; off <<= 1) t += __shfl_xor(t, off, 64);
            if ((c & 31) == 0) ws[OFF_CL + (c >> 5) * NN + (i0 + r)] = 0.6f * t;
        }
    } else {
        int doff = (which == 1) ? OFF_WRH : OFF_WVH;
        // transposed-tiled: element (j, c) -> [c>>2][j][c&3]
        #pragma unroll
        for (int r = 0; r < 4; r++)
            ws[doff + (c >> 2) * (NN * 4) + (i0 + r) * 4 + (c & 3)] = a[r];
        if (which == 1) {
            float att = ws[OFF_ATT + l * HDD + (c & 31)];
            #pragma unroll
            for (int r = 0; r < 4; r++) {
                float t = att * a[r];
                #pragma unroll
                for (int off = 1; off < 32; off <<= 1) t += __shfl_xor(t, off, 64);
                if ((c & 31) == 0) ws[OFF_CR + (c >> 5) * NN + (i0 + r)] = 0.6f * t;
            }
        }
    }
}

// ---- per layer: fused attention, 4-node-tiled, two-pass, LDS-STAGED ----
// Block = 512 threads = 8 waves, 4 NODES per block (grid 256 = 1 block/CU).
// Wave w: head h = w&3, node-pair p = w>>2 -> nodes iA=i0+2p, iB=iA+1.
// e_ij = 0.6*att.(wl_i+wr_j) + sum_d 0.4*att_d*|wl_id + wr_jd|  (exact leaky split)
//
// r6/r7/r8 lesson (3x): this kernel CANNOT buy latency-hiding with registers —
// every added in-flight float4 or live array pushed the allocator into AGPR
// shuttling (v_accvgpr moves in the hot loop) and regressed. So buy it with
// LDS: double-buffered global_load_lds staging. Per jc, the 32 (head,dq)
// 1KB tiles are staged ONCE per block (waves p=0/p=1 share their head's tile
// -> L2 traffic halves, 512->256 MB/dispatch); loads occupy no VGPRs; the
// vmcnt(0) inside __syncthreads() drains the prefetch (T3 minimal recipe).
// Register state stays at the proven r5 level (~52 VGPR).
__global__ __launch_bounds__(512) void k_attn(float* ws, int l) {
    int t = threadIdx.x;
    int i0 = blockIdx.x * 4;
    int lane = t & 63;
    int w = t >> 6;
    int h = __builtin_amdgcn_readfirstlane(w & 3);
    int p = __builtin_amdgcn_readfirstlane(w >> 2);
    int iA = i0 + 2 * p, iB = iA + 1;

    __shared__ float stageS[2][32][256]; // 64 KB: 2 bufs x 32 (h*8+dq) tiles x 64 lanes x 4f
    __shared__ unsigned mrow[4][32];
    __shared__ float ebuf[8][64][33];    // 67.6 KB: e-store, then acc-reduce scratch
    __shared__ float invs[4][4];         // [node][head]
    __shared__ float agg_s[4][HID];
    __shared__ float red2[4][2][2];

    if (t < 128) mrow[t >> 5][t & 31] = ((const unsigned*)(ws + OFF_MASK))[i0 * 32 + t];

    // wave-uniform vectors -> registers (0.4 folded into att)
    float att_r[32], wlA[32], wlB[32];
    const float* attp = ws + OFF_ATT + l * HDD;
    const float* wlpA = ws + OFF_WLH + iA * HID + h * HDD;
    const float* wlpB = ws + OFF_WLH + iB * HID + h * HDD;
    #pragma unroll
    for (int d = 0; d < 32; d++) {
        att_r[d] = 0.4f * attp[d];
        wlA[d] = wlpA[d];
        wlB[d] = wlpB[d];
    }
    float clA = ws[OFF_CL + h * NN + iA];
    float clB = ws[OFF_CL + h * NN + iB];
    const float* crp = ws + OFF_CR + h * NN;

    // staging bases: this wave stages tiles (h, dq = p*4 + k), k=0..3.
    // global tile (h,dq) = floats [base + (h*8+dq)*4096 + jc*256 + lane*4 .. +3]
    const float* gwr = ws + OFF_WRH + (h * 8 + p * 4) * (NN * 4) + lane * 4;
    const float* gwv = ws + OFF_WVH + (h * 8 + p * 4) * (NN * 4) + lane * 4;
    #define STAGE(gbase, jc, buf)                                              \
        _Pragma("unroll")                                                      \
        for (int k = 0; k < 4; k++)                                            \
            gld_lds16((gbase) + k * (NN * 4) + (jc) * 256,                     \
                      &stageS[(buf)][h * 8 + p * 4 + k][0]);

    __syncthreads();     // mrow visible

    // per-lane 16-bit adjacency masks for both nodes: bit jc = adj of j=jc*64+lane
    unsigned mbA = 0, mbB = 0;
    #pragma unroll
    for (int jc = 0; jc < 16; jc++) {
        int wi = jc * 2 + (lane >> 5);
        mbA |= ((mrow[2 * p][wi] >> (lane & 31)) & 1u) << jc;
        mbB |= ((mrow[2 * p + 1][wi] >> (lane & 31)) & 1u) << jc;
    }

    // pass 1: e for both nodes -> ebuf, track lane maxes. wr tiles via LDS stage.
    STAGE(gwr, 0, 0);
    __syncthreads();     // prologue tile ready
    float mA = -1e30f, mB = -1e30f;
    #pragma unroll 1
    for (int jc = 0; jc < 16; jc++) {
        int buf = jc & 1;
        if (jc < 15) STAGE(gwr, jc + 1, buf ^ 1);   // async prefetch, no VGPRs
        float cr6 = crp[jc * 64 + lane];            // needed only at loop end: covered
        const float4* sw = (const float4*)&stageS[buf][h * 8][0];
        float dA = 0.0f, dB = 0.0f;
        #pragma unroll
        for (int dq = 0; dq < 8; dq++) {
            float4 w4 = sw[dq * 64 + lane];         // ds_read_b128, conflict-free
            dA = fmaf(att_r[dq*4+0], fabsf(wlA[dq*4+0] + w4.x), dA);
            dB = fmaf(att_r[dq*4+0], fabsf(wlB[dq*4+0] + w4.x), dB);
            dA = fmaf(att_r[dq*4+1], fabsf(wlA[dq*4+1] + w4.y), dA);
            dB = fmaf(att_r[dq*4+1], fabsf(wlB[dq*4+1] + w4.y), dB);
            dA = fmaf(att_r[dq*4+2], fabsf(wlA[dq*4+2] + w4.z), dA);
            dB = fmaf(att_r[dq*4+2], fabsf(wlB[dq*4+2] + w4.z), dB);
            dA = fmaf(att_r[dq*4+3], fabsf(wlA[dq*4+3] + w4.w), dA);
            dB = fmaf(att_r[dq*4+3], fabsf(wlB[dq*4+3] + w4.w), dB);
        }
        float eA = (clA + cr6) + dA; eA = ((mbA >> jc) & 1u) ? eA : -1e9f;
        float eB = (clB + cr6) + dB; eB = ((mbB >> jc) & 1u) ? eB : -1e9f;
        ebuf[w][lane][jc]      = eA;
        ebuf[w][lane][16 + jc] = eB;
        mA = fmaxf(mA, eA);
        mB = fmaxf(mB, eB);
        __syncthreads();   // drains prefetch (vmcnt0) + all reads of buf done
    }
    #pragma unroll
    for (int off = 32; off > 0; off >>= 1) {
        mA = fmaxf(mA, __shfl_xor(mA, off, 64));
        mB = fmaxf(mB, __shfl_xor(mB, off, 64));
    }

    // pass 2: pe = exp(e - m) (masked -> exact 0), accumulate pe * v.
    // wv tiles via the same stage buffers (pass-1 reads fully drained).
    STAGE(gwv, 0, 0);
    float accA[32], accB[32];
    #pragma unroll
    for (int d = 0; d < 32; d++) { accA[d] = 0.0f; accB[d] = 0.0f; }
    float lsA = 0.0f, lsB = 0.0f;
    __syncthreads();     // pass-2 prologue tile ready
    #pragma unroll 1
    for (int jc = 0; jc < 16; jc++) {
        int buf = jc & 1;
        if (jc < 15) STAGE(gwv, jc + 1, buf ^ 1);
        float peA = __expf(ebuf[w][lane][jc]      - mA);
        float peB = __expf(ebuf[w][lane][16 + jc] - mB);
        lsA += peA; lsB += peB;
        const float4* sv = (const float4*)&stageS[buf][h * 8][0];
        #pragma unroll
        for (int dq = 0; dq < 8; dq++) {
            float4 v4 = sv[dq * 64 + lane];
            accA[dq*4+0] = fmaf(peA, v4.x, accA[dq*4+0]);
            accB[dq*4+0] = fmaf(peB, v4.x, accB[dq*4+0]);
            accA[dq*4+1] = fmaf(peA, v4.y, accA[dq*4+1]);
            accB[dq*4+1] = fmaf(peB, v4.y, accB[dq*4+1]);
            accA[dq*4+2] = fmaf(peA, v4.z, accA[dq*4+2]);
            accB[dq*4+2] = fmaf(peB, v4.z, accB[dq*4+2]);
            accA[dq*4+3] = fmaf(peA, v4.w, accA[dq*4+3]);
            accB[dq*4+3] = fmaf(peB, v4.w, accB[dq*4+3]);
        }
        __syncthreads();
    }
    #pragma unroll
    for (int off = 32; off > 0; off >>= 1) {
        lsA += __shfl_xor(lsA, off, 64);
        lsB += __shfl_xor(lsB, off, 64);
    }
    if (lane == 0) {
        invs[2 * p][h]     = 1.0f / lsA;
        invs[2 * p + 1][h] = 1.0f / lsB;
    }
    __syncthreads();   // all ebuf e-reads done; ebuf reusable; invs visible

    // acc cross-lane reduce via LDS, 2 rounds (node = 2p + r); region = p*4+h
    float* rbuf = &ebuf[0][0][0];
    {   // round r=0: node iA
        int reg = p * 4 + h;
        #pragma unroll
        for (int d = 0; d < 32; d++) rbuf[(reg * 64 + lane) * 33 + d] = accA[d];
        __syncthreads();
        int g = t >> 6, d = lane & 31, half = lane >> 5;
        float s = 0.0f;
        #pragma unroll
        for (int lq = 0; lq < 32; lq++) s += rbuf[(g * 64 + half * 32 + lq) * 33 + d];
        s += __shfl_xor(s, 32, 64);
        int node = 2 * (g >> 2), hh = g & 3;
        if (half == 0) agg_s[node][hh * 32 + d] = s * invs[node][hh];
        __syncthreads();
    }
    {   // round r=1: node iB
        int reg = p * 4 + h;
        #pragma unroll
        for (int d = 0; d < 32; d++) rbuf[(reg * 64 + lane) * 33 + d] = accB[d];
        __syncthreads();
        int g = t >> 6, d = lane & 31, half = lane >> 5;
        float s = 0.0f;
        #pragma unroll
        for (int lq = 0; lq < 32; lq++) s += rbuf[(g * 64 + half * 32 + lq) * 33 + d];
        s += __shfl_xor(s, 32, 64);
        int node = 2 * (g >> 2) + 1, hh = g & 3;
        if (half == 0) agg_s[node][hh * 32 + d] = s * invs[node][hh];
        __syncthreads();
    }

    // layernorm + residual for the 4 nodes: t -> node n=t>>7, feature f=t&127
    {
        int n = t >> 7, f = t & 127;
        float agg = agg_s[n][f];
        float s = agg, s2 = agg * agg;
        #pragma unroll
        for (int off = 32; off > 0; off >>= 1) {
            s  += __shfl_xor(s,  off, 64);
            s2 += __shfl_xor(s2, off, 64);
        }
        int half = (t >> 6) & 1;
        if (lane == 0) { red2[n][half][0] = s; red2[n][half][1] = s2; }
        __syncthreads();
        float ts  = red2[n][0][0] + red2[n][1][0];
        float ts2 = red2[n][0][1] + red2[n][1][1];
        float mu  = ts  * (1.0f / HID);
        float var = ts2 * (1.0f / HID) - mu * mu;
        float gm = ws[OFF_GAM + l * HID + f];
        float be = ws[OFF_BET + l * HID + f];
        float o = (agg - mu) * rsqrtf(var + 1e-5f) * gm + be;
        ws[OFF_H + (i0 + n) * HID + f] += fmaxf(o, 0.0f);
    }
    #undef STAGE
}

// ---- fused epilogue, 1024 threads/block ----
// blocks 0..63: node_logits + delta_mu heads, 16 nodes/block (wave = node).
// block 64: pooled mean (8 row-groups x 128 rows, unroll-16 ILP) + value head.
__global__ __launch_bounds__(1024) void k_post(float* ws, const unsigned* nf, void* out) {
    bool bf = detect_bf(nf);
    int b = blockIdx.x, t = threadIdx.x;
    if (b < 64) {
        __shared__ float hrow[16][HID];
        int n = t >> 6, tt = t & 63;
        int i = b * 16 + n;
        hrow[n][tt]      = ws[OFF_H + i * HID + tt];
        hrow[n][tt + 64] = ws[OFF_H + i * HID + tt + 64];
        __syncthreads();
        const float* Wn1 = ws + OFF_WN1;
        const float* Wd1 = ws + OFF_WD1;
        float z1 = ws[OFF_BN1 + tt], zd = ws[OFF_BD1 + tt];
        #pragma unroll 4
        for (int k = 0; k < HID; k++) {
            float hk = hrow[n][k];
            z1 += hk * Wn1[k * 64 + tt];
            zd += hk * Wd1[k * 64 + tt];
        }
        z1 = fmaxf(z1, 0.0f); zd = fmaxf(zd, 0.0f);
        float lg = z1 * ws[OFF_WN2 + tt];
        float d0 = zd * ws[OFF_WD2 + tt * 2 + 0];
        float d1 = zd * ws[OFF_WD2 + tt * 2 + 1];
        #pragma unroll
        for (int off = 32; off > 0; off >>= 1) {
            lg += __shfl_xor(lg, off, 64);
            d0 += __shfl_xor(d0, off, 64);
            d1 += __shfl_xor(d1, off, 64);
        }
        if (tt == 0) {
            store_out(out, i,              lg + ws[OFF_BN2],     bf);
            store_out(out, NN + i * 2 + 0, d0 + ws[OFF_BD2 + 0], bf);
            store_out(out, NN + i * 2 + 1, d1 + ws[OFF_BD2 + 1], bf);
        }
    } else {
        __shared__ float part[8][HID];
        __shared__ float pooled[HID];
        int g = t >> 7, c = t & 127;
        float s = 0.0f;
        #pragma unroll 16
        for (int r = 0; r < 128; r++) s += ws[OFF_H + (g * 128 + r) * HID + c];
        part[g][c] = s;
        __syncthreads();
        if (t < HID) {
            float p = 0.0f;
            #pragma unroll
            for (int gg = 0; gg < 8; gg++) p += part[gg][t];
            pooled[t] = p * (1.0f / NN);
        }
        __syncthreads();
        if (t < 64) {
            float z = ws[OFF_BV1 + t];
            float z1 = 0.0f;
            #pragma unroll 8
            for (int k = 0; k < HID; k += 2) {
                z  += pooled[k]     * ws[OFF_WV1 + k * 64 + t];
                z1 += pooled[k + 1] * ws[OFF_WV1 + (k + 1) * 64 + t];
            }
            z = fmaxf(z + z1, 0.0f);
            float pv = z * ws[OFF_WV2 + t];
            #pragma unroll
            for (int off = 32; off > 0; off >>= 1) pv += __shfl_xor(pv, off, 64);
            if (t == 0) store_out(out, 3072, pv + ws[OFF_BV2], bf);
        }
    }
}

extern "C" void kernel_launch(void* const* d_in, const int* in_sizes, int n_in,
                              void* d_out, int out_size, void* d_ws, size_t ws_size,
                              hipStream_t stream) {
    float* ws = (float*)d_ws;
    const unsigned* nf = (const unsigned*)d_in[0];

    P21 ptrs;
    const int map[21] = {0,2,3,4,5,6,7,8,9,10,11,12,13,14,15,16,17,18,19,20,21};
    for (int s = 0; s < 21; s++) ptrs.p[s] = d_in[map[s]];

    // prologue: convert (CB blocks) | mask (NN blocks) | h0 (NN/2 blocks)
    k_pre<<<CB + NN + NN / 2, 256, 0, stream>>>(ptrs, d_in[1], nf, ws);

    for (int l = 0; l < NL; l++) {
        k_mm3<<<dim3(NN / 4, 3), 128, 0, stream>>>(ws, l);
        k_attn<<<NN / 4, 512, 0, stream>>>(ws, l);
    }

    k_post<<<65, 1024, 0, stream>>>(ws, nf, d_out);
}

// Round 10
// 227.221 us; speedup vs baseline: 1.6699x; 1.0948x over previous
//
#include <hip/hip_runtime.h>
#include <hip/hip_bf16.h>

#define NN 1024
#define HID 128
#define NHEADS 4
#define HDD 32
#define NL 3

// ---- ws layout (float-word units) ----
constexpr int OFF_CONV = 16;
constexpr int OFF_NF   = OFF_CONV;            // 3072
constexpr int OFF_WP   = OFF_NF  + 3072;      // 384
constexpr int OFF_BP   = OFF_WP  + 384;       // 128
constexpr int OFF_WL   = OFF_BP  + 128;       // 49152
constexpr int OFF_WR   = OFF_WL  + 49152;     // 49152
constexpr int OFF_WVW  = OFF_WR  + 49152;     // 49152
constexpr int OFF_ATT  = OFF_WVW + 49152;     // 96
constexpr int OFF_GAM  = OFF_ATT + 96;        // 384
constexpr int OFF_BET  = OFF_GAM + 384;       // 384
constexpr int OFF_WN1  = OFF_BET + 384;       // 8192
constexpr int OFF_BN1  = OFF_WN1 + 8192;      // 64
constexpr int OFF_WN2  = OFF_BN1 + 64;        // 64
constexpr int OFF_BN2  = OFF_WN2 + 64;        // 1
constexpr int OFF_WD1  = OFF_BN2 + 1;         // 8192
constexpr int OFF_BD1  = OFF_WD1 + 8192;      // 64
constexpr int OFF_WD2  = OFF_BD1 + 64;        // 128
constexpr int OFF_BD2  = OFF_WD2 + 128;       // 2
constexpr int OFF_WV1  = OFF_BD2 + 2;         // 8192
constexpr int OFF_BV1  = OFF_WV1 + 8192;      // 64
constexpr int OFF_WV2  = OFF_BV1 + 64;        // 64
constexpr int OFF_BV2  = OFF_WV2 + 64;        // 1
constexpr int OFF_CONV_END = OFF_BV2 + 1;
constexpr int CONV_TOTAL = OFF_CONV_END - OFF_CONV;
constexpr int CB = (CONV_TOTAL + 255) / 256;  // convert blocks in k_pre
constexpr int OFF_MASK = 176960;              // 1024*32 uint32 words
constexpr int OFF_H    = OFF_MASK + NN*32;
constexpr int OFF_WLH  = OFF_H   + NN*HID;    // normal [i][128]
constexpr int OFF_WRH  = OFF_WLH + NN*HID;    // TRANSPOSED [dq=32][j=1024][4]
constexpr int OFF_WVH  = OFF_WRH + NN*HID;    // TRANSPOSED [dq=32][j=1024][4]
constexpr int OFF_CL   = OFF_WVH + NN*HID;    // [h][i]  0.6*att.wl
constexpr int OFF_CR   = OFF_CL  + NHEADS*NN; // [h][j]  0.6*att.wr

__device__ __forceinline__ float bf2f(unsigned short u) {
    return __uint_as_float(((unsigned)u) << 16);
}
__device__ __forceinline__ void store_out(void* out, int idx, float v, bool bf) {
    if (bf) {
        unsigned u = __float_as_uint(v);
        unsigned r = (u + 0x7FFFu + ((u >> 16) & 1u)) >> 16;
        ((unsigned short*)out)[idx] = (unsigned short)r;
    } else {
        ((float*)out)[idx] = v;
    }
}
__device__ __forceinline__ float ldraw(const void* p, int idx, bool bf) {
    return bf ? bf2f(((const unsigned short*)p)[idx]) : ((const float*)p)[idx];
}
// per-wave dtype sniff: fp32 normals have exponent field in [110,140];
// packed bf16 pairs viewed as fp32 essentially never do. Call from ALL lanes.
__device__ __forceinline__ bool detect_bf(const unsigned* nf) {
    unsigned w = nf[threadIdx.x & 63];
    int e = (int)((w >> 23) & 0xFFu);
    unsigned long long b = __ballot(e >= 110 && e <= 140);
    return __popcll(b) < 32;
}

struct P21 { const void* p[21]; };
__device__ const int g_sizes[21] = {3072,384,128,49152,49152,49152,96,384,384,
                                    8192,64,64,1,8192,64,128,2,8192,64,64,1};
__device__ const int g_dsts[21] = {OFF_NF,OFF_WP,OFF_BP,OFF_WL,OFF_WR,OFF_WVW,OFF_ATT,
                                   OFF_GAM,OFF_BET,OFF_WN1,OFF_BN1,OFF_WN2,OFF_BN2,
                                   OFF_WD1,OFF_BD1,OFF_WD2,OFF_BD2,OFF_WV1,OFF_BV1,
                                   OFF_WV2,OFF_BV2};

// ---- fused prologue: param convert | adj->bitmask | h0  (all independent:
// h0 reads RAW nf/Wp/bp with its own bf16 handling, so no ordering needed) ----
__global__ __launch_bounds__(256) void k_pre(P21 in, const void* adj, const unsigned* nf, float* ws) {
    bool bf = detect_bf(nf);
    int b = blockIdx.x, t = threadIdx.x;
    if (b < CB) {
        // convert all non-adj params to fp32 in ws
        int g = b * 256 + t;
        if (g >= CONV_TOTAL) return;
        int rem = g, s = 0;
        while (s < 21 && rem >= g_sizes[s]) { rem -= g_sizes[s]; s++; }
        if (s >= 21) return;
        ws[g_dsts[s] + rem] = ldraw(in.p[s], rem, bf);
    } else if (b < CB + NN) {
        // adj row -> packed bitmask
        int i = b - CB;
        unsigned* mask = (unsigned*)(ws + OFF_MASK);
        int lane = t & 63, wv = t >> 6;
        #pragma unroll
        for (int q = 0; q < 4; q++) {
            int seg = wv * 4 + q;
            int j = seg * 64 + lane;
            float v = ldraw(adj, i * NN + j, bf);
            unsigned long long bl = __ballot(v > 0.5f);
            if (lane == 0) {
                mask[i * 32 + seg * 2]     = (unsigned)bl;
                mask[i * 32 + seg * 2 + 1] = (unsigned)(bl >> 32);
            }
        }
    } else {
        // h0 = relu(nf @ Wp + bp), raw reads: 2 nodes per block
        int bb = b - CB - NN;
        int i = bb * 2 + (t >> 7), c = t & 127;
        float a = ldraw(in.p[2], c, bf);                     // bp
        #pragma unroll
        for (int k = 0; k < 3; k++)
            a += ldraw(in.p[0], i * 3 + k, bf) * ldraw(in.p[1], k * HID + c, bf);
        ws[OFF_H + i * HID + c] = fmaxf(a, 0.0f);
    }
}

// ---- per layer: wlh = h@Wl (normal + cl), wrh/wvh = h@{Wr,Wv} (transposed + cr) ----
__global__ __launch_bounds__(128) void k_mm3(float* ws, int l) {
    __shared__ float hs[4][HID];
    int c = threadIdx.x, i0 = blockIdx.x * 4, which = blockIdx.y;
    const float* h = ws + OFF_H;
    #pragma unroll
    for (int r = 0; r < 4; r++) hs[r][c] = h[(i0 + r) * HID + c];
    __syncthreads();
    int woff = (which == 0) ? OFF_WL : (which == 1) ? OFF_WR : OFF_WVW;
    const float* W = ws + woff + l * HID * HID;
    float a[4] = {0,0,0,0};
    #pragma unroll 4
    for (int k = 0; k < HID; k++) {
        float w = W[k * HID + c];
        #pragma unroll
        for (int r = 0; r < 4; r++) a[r] += hs[r][k] * w;
    }
    if (which == 0) {
        #pragma unroll
        for (int r = 0; r < 4; r++) ws[OFF_WLH + (i0 + r) * HID + c] = a[r];
        float att = ws[OFF_ATT + l * HDD + (c & 31)];
        #pragma unroll
        for (int r = 0; r < 4; r++) {
            float t = att * a[r];
            #pragma unroll
            for (int off = 1; off < 32; off <<= 1) t += __shfl_xor(t, off, 64);
            if ((c & 31) == 0) ws[OFF_CL + (c >> 5) * NN + (i0 + r)] = 0.6f * t;
        }
    } else {
        int doff = (which == 1) ? OFF_WRH : OFF_WVH;
        // transposed-tiled: element (j, c) -> [c>>2][j][c&3]
        #pragma unroll
        for (int r = 0; r < 4; r++)
            ws[doff + (c >> 2) * (NN * 4) + (i0 + r) * 4 + (c & 3)] = a[r];
        if (which == 1) {
            float att = ws[OFF_ATT + l * HDD + (c & 31)];
            #pragma unroll
            for (int r = 0; r < 4; r++) {
                float t = att * a[r];
                #pragma unroll
                for (int off = 1; off < 32; off <<= 1) t += __shfl_xor(t, off, 64);
                if ((c & 31) == 0) ws[OFF_CR + (c >> 5) * NN + (i0 + r)] = 0.6f * t;
            }
        }
    }
}

// ---- per layer: fused attention, 2-node blocks, j-SPLIT for occupancy ----
// Block = 512 threads = 8 waves, 2 NODES per block; grid 512 = 2 blocks/CU
// = 4 waves/SIMD (r5 ran grid 256 = 1 block/CU: no co-resident block, so L2
// latency was exposed at VALUBusy 24%). Wave w: head h = w&3, j-half jh = w>>2
// streams j in [jh*512, jh*512+512). Both j-half waves use the GLOBAL max in
// pass 2 (maxes exchanged via LDS between passes) -> no rescaling anywhere;
// lsum and acc merged in the existing LDS lane-reduce by summing both
// half-regions. Inner loops BYTE-IDENTICAL to r5 (proven ~52 VGPR, no AGPR
// shuttle). L2 traffic unchanged (512 MB/dispatch).
// Failed-lever ledger for this kernel: registers for MLP (r7 online-softmax,
// r8 unroll-2: AGPR shuttle), grid.sync mega-fusion (r6), per-jc LDS staging
// (r9: barrier-serialized). Occupancy was the one untried axis.
// e_ij = 0.6*att.(wl_i+wr_j) + sum_d 0.4*att_d*|wl_id + wr_jd|  (exact leaky split)
__global__ __launch_bounds__(512) void k_attn(float* ws, int l) {
    int t = threadIdx.x;
    int i0 = blockIdx.x * 2;
    int lane = t & 63;
    int w = t >> 6;
    int h  = __builtin_amdgcn_readfirstlane(w & 3);
    int jh = __builtin_amdgcn_readfirstlane(w >> 2);
    int iA = i0, iB = i0 + 1;

    __shared__ unsigned mrow[2][32];
    __shared__ float ebuf[8][64][33];   // 67.6 KB: e-store, then acc-reduce scratch
    __shared__ float mex[2][4][2];      // [jh][head][node] partial maxes
    __shared__ float lsx[2][4][2];      // [jh][head][node] partial sums
    __shared__ float agg_s[2][HID];
    __shared__ float red2[2][2][2];

    if (t < 64) mrow[t >> 5][t & 31] = ((const unsigned*)(ws + OFF_MASK))[i0 * 32 + t];
    __syncthreads();

    // per-lane 8-bit adjacency masks: bit jc = adj of j = jh*512 + jc*64 + lane
    unsigned mbA = 0, mbB = 0;
    #pragma unroll
    for (int jc = 0; jc < 8; jc++) {
        int wi = jh * 16 + jc * 2 + (lane >> 5);
        mbA |= ((mrow[0][wi] >> (lane & 31)) & 1u) << jc;
        mbB |= ((mrow[1][wi] >> (lane & 31)) & 1u) << jc;
    }

    // wave-uniform vectors -> registers (0.4 folded into att)
    float att_r[32], wlA[32], wlB[32];
    const float* attp = ws + OFF_ATT + l * HDD;
    const float* wlpA = ws + OFF_WLH + iA * HID + h * HDD;
    const float* wlpB = ws + OFF_WLH + iB * HID + h * HDD;
    #pragma unroll
    for (int d = 0; d < 32; d++) {
        att_r[d] = 0.4f * attp[d];
        wlA[d] = wlpA[d];
        wlB[d] = wlpB[d];
    }
    float clA = ws[OFF_CL + h * NN + iA];
    float clB = ws[OFF_CL + h * NN + iB];

    const float* wrT = ws + OFF_WRH + h * 8 * (NN * 4) + jh * 2048 + lane * 4;
    const float* wvT = ws + OFF_WVH + h * 8 * (NN * 4) + jh * 2048 + lane * 4;
    const float* crp = ws + OFF_CR + h * NN + jh * 512;

    // pass 1: e for both nodes over this wave's j-half -> LDS, track lane maxes
    float mA = -1e30f, mB = -1e30f;
    #pragma unroll 1
    for (int jc = 0; jc < 8; jc++) {
        float cr6 = crp[jc * 64 + lane];
        float dA = 0.0f, dB = 0.0f;
        #pragma unroll
        for (int dq = 0; dq < 8; dq++) {
            float4 wv4 = *(const float4*)(wrT + dq * (NN * 4) + jc * 256);
            dA = fmaf(att_r[dq*4+0], fabsf(wlA[dq*4+0] + wv4.x), dA);
            dB = fmaf(att_r[dq*4+0], fabsf(wlB[dq*4+0] + wv4.x), dB);
            dA = fmaf(att_r[dq*4+1], fabsf(wlA[dq*4+1] + wv4.y), dA);
            dB = fmaf(att_r[dq*4+1], fabsf(wlB[dq*4+1] + wv4.y), dB);
            dA = fmaf(att_r[dq*4+2], fabsf(wlA[dq*4+2] + wv4.z), dA);
            dB = fmaf(att_r[dq*4+2], fabsf(wlB[dq*4+2] + wv4.z), dB);
            dA = fmaf(att_r[dq*4+3], fabsf(wlA[dq*4+3] + wv4.w), dA);
            dB = fmaf(att_r[dq*4+3], fabsf(wlB[dq*4+3] + wv4.w), dB);
        }
        float eA = (clA + cr6) + dA; eA = ((mbA >> jc) & 1u) ? eA : -1e9f;
        float eB = (clB + cr6) + dB; eB = ((mbB >> jc) & 1u) ? eB : -1e9f;
        ebuf[w][lane][jc]     = eA;
        ebuf[w][lane][8 + jc] = eB;
        mA = fmaxf(mA, eA);
        mB = fmaxf(mB, eB);
    }
    #pragma unroll
    for (int off = 32; off > 0; off >>= 1) {
        mA = fmaxf(mA, __shfl_xor(mA, off, 64));
        mB = fmaxf(mB, __shfl_xor(mB, off, 64));
    }
    // merge maxes across the two j-half waves of this head -> GLOBAL max
    if (lane == 0) { mex[jh][h][0] = mA; mex[jh][h][1] = mB; }
    __syncthreads();
    mA = fmaxf(mex[0][h][0], mex[1][h][0]);
    mB = fmaxf(mex[0][h][1], mex[1][h][1]);

    // pass 2: pe = exp(e - m_global) (masked -> exact 0), accumulate pe * v
    float accA[32], accB[32];
    #pragma unroll
    for (int d = 0; d < 32; d++) { accA[d] = 0.0f; accB[d] = 0.0f; }
    float lsA = 0.0f, lsB = 0.0f;
    #pragma unroll 1
    for (int jc = 0; jc < 8; jc++) {
        float peA = __expf(ebuf[w][lane][jc]     - mA);
        float peB = __expf(ebuf[w][lane][8 + jc] - mB);
        lsA += peA; lsB += peB;
        #pragma unroll
        for (int dq = 0; dq < 8; dq++) {
            float4 v4 = *(const float4*)(wvT + dq * (NN * 4) + jc * 256);
            accA[dq*4+0] = fmaf(peA, v4.x, accA[dq*4+0]);
            accB[dq*4+0] = fmaf(peB, v4.x, accB[dq*4+0]);
            accA[dq*4+1] = fmaf(peA, v4.y, accA[dq*4+1]);
            accB[dq*4+1] = fmaf(peB, v4.y, accB[dq*4+1]);
            accA[dq*4+2] = fmaf(peA, v4.z, accA[dq*4+2]);
            accB[dq*4+2] = fmaf(peB, v4.z, accB[dq*4+2]);
            accA[dq*4+3] = fmaf(peA, v4.w, accA[dq*4+3]);
            accB[dq*4+3] = fmaf(peB, v4.w, accB[dq*4+3]);
        }
    }
    #pragma unroll
    for (int off = 32; off > 0; off >>= 1) {
        lsA += __shfl_xor(lsA, off, 64);
        lsB += __shfl_xor(lsB, off, 64);
    }
    if (lane == 0) { lsx[jh][h][0] = lsA; lsx[jh][h][1] = lsB; }

    // acc cross-lane + cross-j-half reduce via LDS, 2 rounds (nodes A, B).
    // Wave w's partials live in region w = jh*4 + h; reducer group g (<4)
    // sums regions g and g+4 (both j-halves of head g). Same global m on both
    // halves -> plain sums, no rescale. lsx written before the same barrier.
    float* rbuf = &ebuf[0][0][0];
    {   // round 0: node iA
        #pragma unroll
        for (int d = 0; d < 32; d++) rbuf[(w * 64 + lane) * 33 + d] = accA[d];
        __syncthreads();
        int g = t >> 6, d = lane & 31, halfl = lane >> 5;
        if (g < 4) {
            float s = 0.0f;
            #pragma unroll
            for (int lq = 0; lq < 32; lq++) {
                s += rbuf[(g * 64       + halfl * 32 + lq) * 33 + d];
                s += rbuf[((g + 4) * 64 + halfl * 32 + lq) * 33 + d];
            }
            s += __shfl_xor(s, 32, 64);
            if (halfl == 0)
                agg_s[0][g * 32 + d] = s * (1.0f / (lsx[0][g][0] + lsx[1][g][0]));
        }
        __syncthreads();
    }
    {   // round 1: node iB
        #pragma unroll
        for (int d = 0; d < 32; d++) rbuf[(w * 64 + lane) * 33 + d] = accB[d];
        __syncthreads();
        int g = t >> 6, d = lane & 31, halfl = lane >> 5;
        if (g < 4) {
            float s = 0.0f;
            #pragma unroll
            for (int lq = 0; lq < 32; lq++) {
                s += rbuf[(g * 64       + halfl * 32 + lq) * 33 + d];
                s += rbuf[((g + 4) * 64 + halfl * 32 + lq) * 33 + d];
            }
            s += __shfl_xor(s, 32, 64);
            if (halfl == 0)
                agg_s[1][g * 32 + d] = s * (1.0f / (lsx[0][g][1] + lsx[1][g][1]));
        }
        __syncthreads();
    }

    // layernorm + residual for the 2 nodes. Threads 256..511 mirror 0..255
    // (same shuffle math, no stores) so all barriers stay convergent.
    {
        int n = (t >> 7) & 1, f = t & 127;
        float agg = agg_s[n][f];
        float s = agg, s2 = agg * agg;
        #pragma unroll
        for (int off = 32; off > 0; off >>= 1) {
            s  += __shfl_xor(s,  off, 64);
            s2 += __shfl_xor(s2, off, 64);
        }
        int halfw = (t >> 6) & 1;
        if (lane == 0 && t < 256) { red2[n][halfw][0] = s; red2[n][halfw][1] = s2; }
        __syncthreads();
        float ts  = red2[n][0][0] + red2[n][1][0];
        float ts2 = red2[n][0][1] + red2[n][1][1];
        float mu  = ts  * (1.0f / HID);
        float var = ts2 * (1.0f / HID) - mu * mu;
        float gm = ws[OFF_GAM + l * HID + f];
        float be = ws[OFF_BET + l * HID + f];
        float o = (agg - mu) * rsqrtf(var + 1e-5f) * gm + be;
        if (t < 256) ws[OFF_H + (i0 + n) * HID + f] += fmaxf(o, 0.0f);
    }
}

// ---- fused epilogue, 1024 threads/block ----
// blocks 0..63: node_logits + delta_mu heads, 16 nodes/block (wave = node).
// block 64: pooled mean (8 row-groups x 128 rows, unroll-16 ILP) + value head.
__global__ __launch_bounds__(1024) void k_post(float* ws, const unsigned* nf, void* out) {
    bool bf = detect_bf(nf);
    int b = blockIdx.x, t = threadIdx.x;
    if (b < 64) {
        __shared__ float hrow[16][HID];
        int n = t >> 6, tt = t & 63;
        int i = b * 16 + n;
        hrow[n][tt]      = ws[OFF_H + i * HID + tt];
        hrow[n][tt + 64] = ws[OFF_H + i * HID + tt + 64];
        __syncthreads();
        const float* Wn1 = ws + OFF_WN1;
        const float* Wd1 = ws + OFF_WD1;
        float z1 = ws[OFF_BN1 + tt], zd = ws[OFF_BD1 + tt];
        #pragma unroll 4
        for (int k = 0; k < HID; k++) {
            float hk = hrow[n][k];
            z1 += hk * Wn1[k * 64 + tt];
            zd += hk * Wd1[k * 64 + tt];
        }
        z1 = fmaxf(z1, 0.0f); zd = fmaxf(zd, 0.0f);
        float lg = z1 * ws[OFF_WN2 + tt];
        float d0 = zd * ws[OFF_WD2 + tt * 2 + 0];
        float d1 = zd * ws[OFF_WD2 + tt * 2 + 1];
        #pragma unroll
        for (int off = 32; off > 0; off >>= 1) {
            lg += __shfl_xor(lg, off, 64);
            d0 += __shfl_xor(d0, off, 64);
            d1 += __shfl_xor(d1, off, 64);
        }
        if (tt == 0) {
            store_out(out, i,              lg + ws[OFF_BN2],     bf);
            store_out(out, NN + i * 2 + 0, d0 + ws[OFF_BD2 + 0], bf);
            store_out(out, NN + i * 2 + 1, d1 + ws[OFF_BD2 + 1], bf);
        }
    } else {
        __shared__ float part[8][HID];
        __shared__ float pooled[HID];
        int g = t >> 7, c = t & 127;
        float s = 0.0f;
        #pragma unroll 16
        for (int r = 0; r < 128; r++) s += ws[OFF_H + (g * 128 + r) * HID + c];
        part[g][c] = s;
        __syncthreads();
        if (t < HID) {
            float p = 0.0f;
            #pragma unroll
            for (int gg = 0; gg < 8; gg++) p += part[gg][t];
            pooled[t] = p * (1.0f / NN);
        }
        __syncthreads();
        if (t < 64) {
            float z = ws[OFF_BV1 + t];
            float z1 = 0.0f;
            #pragma unroll 8
            for (int k = 0; k < HID; k += 2) {
                z  += pooled[k]     * ws[OFF_WV1 + k * 64 + t];
                z1 += pooled[k + 1] * ws[OFF_WV1 + (k + 1) * 64 + t];
            }
            z = fmaxf(z + z1, 0.0f);
            float pv = z * ws[OFF_WV2 + t];
            #pragma unroll
            for (int off = 32; off > 0; off >>= 1) pv += __shfl_xor(pv, off, 64);
            if (t == 0) store_out(out, 3072, pv + ws[OFF_BV2], bf);
        }
    }
}

extern "C" void kernel_launch(void* const* d_in, const int* in_sizes, int n_in,
                              void* d_out, int out_size, void* d_ws, size_t ws_size,
                              hipStream_t stream) {
    float* ws = (float*)d_ws;
    const unsigned* nf = (const unsigned*)d_in[0];

    P21 ptrs;
    const int map[21] = {0,2,3,4,5,6,7,8,9,10,11,12,13,14,15,16,17,18,19,20,21};
    for (int s = 0; s < 21; s++) ptrs.p[s] = d_in[map[s]];

    // prologue: convert (CB blocks) | mask (NN blocks) | h0 (NN/2 blocks)
    k_pre<<<CB + NN + NN / 2, 256, 0, stream>>>(ptrs, d_in[1], nf, ws);

    for (int l = 0; l < NL; l++) {
        k_mm3<<<dim3(NN / 4, 3), 128, 0, stream>>>(ws, l);
        k_attn<<<NN / 2, 512, 0, stream>>>(ws, l);
    }

    k_post<<<65, 1024, 0, stream>>>(ws, nf, d_out);
}